// Round 2
// baseline (2203.768 us; speedup 1.0000x reference)
//
#include <hip/hip_runtime.h>
#include <hip/hip_bf16.h>

typedef __hip_bfloat16 bf16;

#define NE 524288
#define NA 16384
#define EPB 16  // edges per block in the edge kernel

__device__ __forceinline__ float b2f(bf16 x) { return __bfloat162float(x); }

// Generic load: f32 flag chooses interpretation. Branch is wave-uniform.
__device__ __forceinline__ float ld(const void* p, long i, int f32) {
    return f32 ? ((const float*)p)[i] : __bfloat162float(((const bf16*)p)[i]);
}

// ---------------------------------------------------------------------------
// Dtype detector: reinterpret Wp2 (glorot, std=1/16, |v| < ~0.5) as bf16.
// If the underlying data is f32, even-indexed "bf16" elements are low mantissa
// halves of floats -> effectively uniform 16-bit patterns -> some decode to
// exponent >= 131 (|v| >= 16 or inf/nan) with near-certainty over 1024 samples.
// flag = 1 means "data is float32".
// ---------------------------------------------------------------------------
__global__ void detect_dtype_kernel(const unsigned short* __restrict__ w,
                                    int* __restrict__ flag) {
    const int t = threadIdx.x;  // 64 threads = 1 wave
    int bad = 0;
    for (int i = t; i < 1024; i += 64) {
        const int e = (w[i] >> 7) & 0xFF;  // bf16 exponent field
        if (e >= 131) bad = 1;             // |v| >= 16, inf, or nan
    }
    const unsigned long long m = __ballot(bad);
    if (t == 0) *flag = (m != 0ull) ? 1 : 0;
}

// ---------------------------------------------------------------------------
// Stage 1: per-edge MLP 4 -> 256 -> 256 -> 64 (relu, relu, none) + analytic
// barrier contribution, then run-compressed atomicAdd scatter into agg/bar.
// ---------------------------------------------------------------------------
__global__ __launch_bounds__(256) void edge_mlp_kernel(
    const void* __restrict__ ef, const int* __restrict__ ids,
    const void* __restrict__ Wp1, const void* __restrict__ bp1,
    const void* __restrict__ Wp2, const void* __restrict__ bp2,
    const void* __restrict__ Wp3, const void* __restrict__ bp3,
    float* __restrict__ agg, float* __restrict__ bar,
    const int* __restrict__ flag)
{
    __shared__ __align__(16) float x[EPB][4];
    __shared__ int   sid[EPB];
    __shared__ float cb[EPB][2];
    __shared__ __align__(16) float h1[EPB][256];
    __shared__ __align__(16) float h2[EPB][256];
    __shared__ __align__(16) float h3[EPB][64];

    const int t = threadIdx.x;
    const long e0 = (long)blockIdx.x * EPB;
    const int f32 = *flag;

    if (t < EPB * 4) x[t >> 2][t & 3] = ld(ef, e0 * 4 + t, f32);
    if (t < EPB)     sid[t] = ids[e0 + t];
    __syncthreads();

    // ---- layer 1: h1[e][t] = relu(x[e] . Wp1[:,t] + bp1[t]) ----
    {
        const float w0 = ld(Wp1, 0 * 256 + t, f32);
        const float w1 = ld(Wp1, 1 * 256 + t, f32);
        const float w2 = ld(Wp1, 2 * 256 + t, f32);
        const float w3 = ld(Wp1, 3 * 256 + t, f32);
        const float b  = ld(bp1, t, f32);
        #pragma unroll
        for (int e = 0; e < EPB; ++e) {
            float v = fmaf(x[e][0], w0,
                      fmaf(x[e][1], w1,
                      fmaf(x[e][2], w2,
                      fmaf(x[e][3], w3, b))));
            h1[e][t] = v > 0.f ? v : 0.f;
        }
    }
    // barrier contribution: -(p/d)/(d - 0.18) = -p / (d*(d-0.18))
    if (t >= 64 && t < 64 + EPB) {
        const int e = t - 64;
        const float px = x[e][0], py = x[e][1];
        const float d = sqrtf(px * px + py * py);
        const float inv = 1.0f / (d * (d - 0.18f));
        cb[e][0] = -px * inv;
        cb[e][1] = -py * inv;
    }
    __syncthreads();

    // ---- layer 2: h2[e][t] = relu(h1[e] . Wp2[:,t] + bp2[t]) ----
    {
        float acc[EPB];
        const float b = ld(bp2, t, f32);
        #pragma unroll
        for (int e = 0; e < EPB; ++e) acc[e] = b;
        for (int k = 0; k < 256; k += 4) {
            const float w0 = ld(Wp2, (long)(k + 0) * 256 + t, f32);
            const float w1 = ld(Wp2, (long)(k + 1) * 256 + t, f32);
            const float w2 = ld(Wp2, (long)(k + 2) * 256 + t, f32);
            const float w3 = ld(Wp2, (long)(k + 3) * 256 + t, f32);
            #pragma unroll
            for (int e = 0; e < EPB; ++e) {
                const float4 h = *(const float4*)&h1[e][k];
                acc[e] = fmaf(h.x, w0, fmaf(h.y, w1, fmaf(h.z, w2, fmaf(h.w, w3, acc[e]))));
            }
        }
        #pragma unroll
        for (int e = 0; e < EPB; ++e) h2[e][t] = acc[e] > 0.f ? acc[e] : 0.f;
    }
    __syncthreads();

    // ---- layer 3: h3[e][o] = h2[e] . Wp3[:,o] + bp3[o]  (no relu) ----
    {
        const int o = t & 63;      // output feature
        const int g = t >> 6;      // edge group: edges g*4 .. g*4+3
        float acc[4];
        const float b = ld(bp3, o, f32);
        #pragma unroll
        for (int i = 0; i < 4; ++i) acc[i] = b;
        for (int k = 0; k < 256; k += 4) {
            const float w0 = ld(Wp3, (long)(k + 0) * 64 + o, f32);
            const float w1 = ld(Wp3, (long)(k + 1) * 64 + o, f32);
            const float w2 = ld(Wp3, (long)(k + 2) * 64 + o, f32);
            const float w3 = ld(Wp3, (long)(k + 3) * 64 + o, f32);
            #pragma unroll
            for (int i = 0; i < 4; ++i) {
                const float4 h = *(const float4*)&h2[g * 4 + i][k];
                acc[i] = fmaf(h.x, w0, fmaf(h.y, w1, fmaf(h.z, w2, fmaf(h.w, w3, acc[i]))));
            }
        }
        #pragma unroll
        for (int i = 0; i < 4; ++i) h3[g * 4 + i][o] = acc[i];
    }
    __syncthreads();

    // ---- scatter with run-length compression (ids sorted) ----
    if (t < 64) {
        int cur = sid[0];
        float local = h3[0][t];
        #pragma unroll
        for (int e = 1; e < EPB; ++e) {
            const int id = sid[e];
            const float v = h3[e][t];
            if (id == cur) {
                local += v;
            } else {
                atomicAdd(&agg[(long)cur * 64 + t], local);
                cur = id;
                local = v;
            }
        }
        atomicAdd(&agg[(long)cur * 64 + t], local);
    } else if (t < 66) {
        const int f = t - 64;
        int cur = sid[0];
        float local = cb[0][f];
        #pragma unroll
        for (int e = 1; e < EPB; ++e) {
            const int id = sid[e];
            const float v = cb[e][f];
            if (id == cur) {
                local += v;
            } else {
                atomicAdd(&bar[cur * 2 + f], local);
                cur = id;
                local = v;
            }
        }
        atomicAdd(&bar[cur * 2 + f], local);
    }
}

// ---------------------------------------------------------------------------
// Stage 2: per-agent MLP 64 -> 256 -> 256 -> 2, plus barrier term.
// ---------------------------------------------------------------------------
__global__ __launch_bounds__(256) void agent_mlp_kernel(
    const float* __restrict__ agg, const float* __restrict__ bar,
    const void* __restrict__ Wr1, const void* __restrict__ br1,
    const void* __restrict__ Wr2, const void* __restrict__ br2,
    const void* __restrict__ Wr3, const void* __restrict__ br3,
    void* __restrict__ out, const int* __restrict__ flag)
{
    __shared__ __align__(16) float a[64];
    __shared__ __align__(16) float r1[256];
    __shared__ float part[2][4];

    const int t = threadIdx.x;
    const int agent = blockIdx.x;
    const int f32 = *flag;

    if (t < 64) a[t] = agg[(long)agent * 64 + t];
    __syncthreads();

    // r1[t] = relu(a . Wr1[:,t] + br1[t])
    float acc = ld(br1, t, f32);
    #pragma unroll
    for (int k = 0; k < 64; ++k) acc = fmaf(a[k], ld(Wr1, (long)k * 256 + t, f32), acc);
    r1[t] = acc > 0.f ? acc : 0.f;
    __syncthreads();

    // r2[t] = relu(r1 . Wr2[:,t] + br2[t])
    float acc2 = ld(br2, t, f32);
    for (int k = 0; k < 256; k += 4) {
        const float4 h = *(const float4*)&r1[k];
        acc2 = fmaf(h.x, ld(Wr2, (long)(k + 0) * 256 + t, f32),
               fmaf(h.y, ld(Wr2, (long)(k + 1) * 256 + t, f32),
               fmaf(h.z, ld(Wr2, (long)(k + 2) * 256 + t, f32),
               fmaf(h.w, ld(Wr2, (long)(k + 3) * 256 + t, f32), acc2))));
    }
    const float r2v = acc2 > 0.f ? acc2 : 0.f;

    // out[o] = r2 . Wr3[:,o] + br3[o] + bar[agent][o]
    float v0 = r2v * ld(Wr3, (long)t * 2 + 0, f32);
    float v1 = r2v * ld(Wr3, (long)t * 2 + 1, f32);
    #pragma unroll
    for (int off = 32; off > 0; off >>= 1) {
        v0 += __shfl_down(v0, off, 64);
        v1 += __shfl_down(v1, off, 64);
    }
    if ((t & 63) == 0) { part[0][t >> 6] = v0; part[1][t >> 6] = v1; }
    __syncthreads();
    if (t < 2) {
        const float s = part[t][0] + part[t][1] + part[t][2] + part[t][3]
                      + ld(br3, t, f32) + bar[agent * 2 + t];
        if (f32) ((float*)out)[agent * 2 + t] = s;
        else     ((bf16*)out)[agent * 2 + t] = __float2bfloat16(s);
    }
}

extern "C" void kernel_launch(void* const* d_in, const int* in_sizes, int n_in,
                              void* d_out, int out_size, void* d_ws, size_t ws_size,
                              hipStream_t stream)
{
    (void)in_sizes; (void)n_in; (void)out_size;

    const void* ef  = d_in[0];
    const int*  ids = (const int*)d_in[1];
    const void* Wp1 = d_in[2];
    const void* bp1 = d_in[3];
    const void* Wp2 = d_in[4];
    const void* bp2 = d_in[5];
    const void* Wp3 = d_in[6];
    const void* bp3 = d_in[7];
    const void* Wr1 = d_in[8];
    const void* br1 = d_in[9];
    const void* Wr2 = d_in[10];
    const void* br2 = d_in[11];
    const void* Wr3 = d_in[12];
    const void* br3 = d_in[13];

    // ws layout: [0,256)   : dtype flag (int)
    //            [256, ...): agg (NA*64 f32) then bar (NA*2 f32)
    const size_t acc_bytes = ((size_t)NA * 64 + (size_t)NA * 2) * sizeof(float);
    const size_t required  = 256 + acc_bytes;
    if (ws_size < required) return;  // diagnostic signature: output stays zero

    int*   flag = (int*)d_ws;
    float* agg  = (float*)((char*)d_ws + 256);
    float* bar  = agg + (size_t)NA * 64;

    detect_dtype_kernel<<<1, 64, 0, stream>>>((const unsigned short*)Wp2, flag);
    hipMemsetAsync(agg, 0, acc_bytes, stream);
    edge_mlp_kernel<<<NE / EPB, 256, 0, stream>>>(ef, ids, Wp1, bp1, Wp2, bp2, Wp3, bp3, agg, bar, flag);
    agent_mlp_kernel<<<NA, 256, 0, stream>>>(agg, bar, Wr1, br1, Wr2, br2, Wr3, br3, d_out, flag);
}

// Round 3
// 779.770 us; speedup vs baseline: 2.8262x; 2.8262x over previous
//
#include <hip/hip_runtime.h>
#include <hip/hip_bf16.h>

typedef __hip_bfloat16 bf16;
typedef __attribute__((ext_vector_type(8))) short short8;   // MFMA A/B frag (8 bf16)
typedef __attribute__((ext_vector_type(4))) float floatx4;  // MFMA C/D frag

#define NE 524288
#define NA 16384
#define E  64        // edges per block in the MFMA edge kernel
#define S1 264       // LDS row stride (shorts) for h1/h2: 256 + 8 pad
#define S3 68        // LDS row stride (floats) for h3: 64 + 4 pad

__device__ __forceinline__ float ld(const void* p, long i, int f32) {
    return f32 ? ((const float*)p)[i] : __bfloat162float(((const bf16*)p)[i]);
}
__device__ __forceinline__ short f2bs(float f) {
    bf16 h = __float2bfloat16(f);
    return *(short*)&h;
}

// ---------------------------------------------------------------------------
// Dtype detector (flag=1 -> tensors are float32). See Round-2 rationale.
// ---------------------------------------------------------------------------
__global__ void detect_dtype_kernel(const unsigned short* __restrict__ w,
                                    int* __restrict__ flag) {
    const int t = threadIdx.x;
    int bad = 0;
    for (int i = t; i < 1024; i += 64) {
        const int e = (w[i] >> 7) & 0xFF;
        if (e >= 131) bad = 1;
    }
    const unsigned long long m = __ballot(bad);
    if (t == 0) *flag = (m != 0ull) ? 1 : 0;
}

// ---------------------------------------------------------------------------
// Weight prep: convert layer-1 weights/biases to f32, transpose Wp2/Wp3 to
// n-major bf16 so MFMA B-fragments are 16B-contiguous loads.
// ---------------------------------------------------------------------------
__global__ void prep_weights_kernel(
    const void* __restrict__ Wp1, const void* __restrict__ bp1,
    const void* __restrict__ Wp2, const void* __restrict__ bp2,
    const void* __restrict__ Wp3, const void* __restrict__ bp3,
    float* __restrict__ Wp1f, float* __restrict__ bp1f,
    float* __restrict__ bp2f, float* __restrict__ bp3f,
    short* __restrict__ Wp2T, short* __restrict__ Wp3T,
    const int* __restrict__ flag)
{
    const int f32 = *flag;
    const int stride = gridDim.x * blockDim.x;
    for (int i = blockIdx.x * blockDim.x + threadIdx.x; i < 83520; i += stride) {
        if (i < 65536) {                      // Wp2T[n][k] = Wp2[k][n]
            const int n = i >> 8, k = i & 255;
            Wp2T[n * 256 + k] = f2bs(ld(Wp2, (long)k * 256 + n, f32));
        } else if (i < 81920) {               // Wp3T[n][k] = Wp3[k][n]
            const int j = i - 65536;
            const int n = j >> 8, k = j & 255;
            Wp3T[n * 256 + k] = f2bs(ld(Wp3, (long)k * 64 + n, f32));
        } else if (i < 82944) {               // Wp1f
            const int j = i - 81920;
            Wp1f[j] = ld(Wp1, j, f32);
        } else if (i < 83200) {               // bp1f
            const int j = i - 82944;
            bp1f[j] = ld(bp1, j, f32);
        } else if (i < 83456) {               // bp2f
            const int j = i - 83200;
            bp2f[j] = ld(bp2, j, f32);
        } else {                              // bp3f
            const int j = i - 83456;
            bp3f[j] = ld(bp3, j, f32);
        }
    }
}

// ---------------------------------------------------------------------------
// Edge MLP via MFMA. 64 edges/block, 256 threads = 4 waves.
//   L1 (K=4)  : VALU, f32, -> h1 bf16 in LDS [64][S1]
//   L2 (K=256): mfma 16x16x32 bf16; per wave 4 M-tiles x 4 N-tiles (n=w*64..)
//   L3 (K=256): per wave M-tile = edges [w*16,w*16+16), N=64 (4 tiles)
//   scatter   : run-length compressed atomics over sorted segment ids
// ---------------------------------------------------------------------------
__global__ __launch_bounds__(256, 2) void edge_mlp_kernel(
    const void* __restrict__ ef, const int* __restrict__ ids,
    const float* __restrict__ Wp1f, const float* __restrict__ bp1f,
    const short* __restrict__ Wp2T, const float* __restrict__ bp2f,
    const short* __restrict__ Wp3T, const float* __restrict__ bp3f,
    float* __restrict__ agg, float* __restrict__ bar,
    const int* __restrict__ flag)
{
    __shared__ __align__(16) float xs[E][4];
    __shared__ int   sid[E];
    __shared__ float cb[E][2];
    __shared__ __align__(16) short h1[E * S1];
    __shared__ __align__(16) short h2[E * S1];
    float* h3 = (float*)h1;   // reuse h1 region after layer 2 (16.4KB < 33.8KB)

    const int t = threadIdx.x;
    const long e0 = (long)blockIdx.x * E;
    const int f32 = *flag;

    // ---- stage inputs ----
    xs[t >> 2][t & 3] = ld(ef, e0 * 4 + t, f32);     // 256 threads = 64 edges x 4
    if (t < E) sid[t] = ids[e0 + t];
    __syncthreads();

    // ---- layer 1 (VALU): h1[e][t] = relu(x[e].Wp1[:,t]+bp1[t]) as bf16 ----
    {
        const float w0 = Wp1f[0 * 256 + t];
        const float w1 = Wp1f[1 * 256 + t];
        const float w2 = Wp1f[2 * 256 + t];
        const float w3 = Wp1f[3 * 256 + t];
        const float b  = bp1f[t];
        #pragma unroll
        for (int e = 0; e < E; ++e) {
            const float4 x = *(const float4*)xs[e];
            float v = fmaf(x.x, w0, fmaf(x.y, w1, fmaf(x.z, w2, fmaf(x.w, w3, b))));
            h1[e * S1 + t] = f2bs(v > 0.f ? v : 0.f);
        }
    }
    if (t < E) {   // barrier contrib: -p / (d*(d-0.18))
        const float px = xs[t][0], py = xs[t][1];
        const float d = sqrtf(px * px + py * py);
        const float inv = 1.0f / (d * (d - 0.18f));
        cb[t][0] = -px * inv;
        cb[t][1] = -py * inv;
    }
    __syncthreads();

    const int wave = t >> 6;
    const int lane = t & 63;
    const int quad = lane >> 4;
    const int ln   = lane & 15;

    // ---- layer 2 (MFMA): h2 = relu(h1 @ Wp2 + bp2) ----
    {
        floatx4 acc[4][4] = {};
        const int nb = wave * 64;                 // this wave's n range
        #pragma unroll 2
        for (int ks = 0; ks < 8; ++ks) {
            const int k = ks * 32 + quad * 8;
            short8 a[4], b[4];
            #pragma unroll
            for (int mt = 0; mt < 4; ++mt)
                a[mt] = *(const short8*)&h1[(mt * 16 + ln) * S1 + k];
            #pragma unroll
            for (int nt = 0; nt < 4; ++nt)
                b[nt] = *(const short8*)&Wp2T[(nb + nt * 16 + ln) * 256 + k];
            #pragma unroll
            for (int mt = 0; mt < 4; ++mt)
                #pragma unroll
                for (int nt = 0; nt < 4; ++nt)
                    acc[mt][nt] = __builtin_amdgcn_mfma_f32_16x16x32_bf16(
                        a[mt], b[nt], acc[mt][nt], 0, 0, 0);
        }
        #pragma unroll
        for (int nt = 0; nt < 4; ++nt) {
            const int n = nb + nt * 16 + ln;
            const float bias = bp2f[n];
            #pragma unroll
            for (int mt = 0; mt < 4; ++mt)
                #pragma unroll
                for (int r = 0; r < 4; ++r) {
                    const int m = mt * 16 + quad * 4 + r;
                    const float v = acc[mt][nt][r] + bias;
                    h2[m * S1 + n] = f2bs(v > 0.f ? v : 0.f);
                }
        }
    }
    __syncthreads();

    // ---- layer 3 (MFMA): h3 = h2 @ Wp3 + bp3 (no relu) ----
    {
        floatx4 acc[4] = {};
        const int mrow = wave * 16 + ln;
        #pragma unroll 2
        for (int ks = 0; ks < 8; ++ks) {
            const int k = ks * 32 + quad * 8;
            const short8 a = *(const short8*)&h2[mrow * S1 + k];
            #pragma unroll
            for (int nt = 0; nt < 4; ++nt) {
                const short8 b = *(const short8*)&Wp3T[(nt * 16 + ln) * 256 + k];
                acc[nt] = __builtin_amdgcn_mfma_f32_16x16x32_bf16(a, b, acc[nt], 0, 0, 0);
            }
        }
        #pragma unroll
        for (int nt = 0; nt < 4; ++nt) {
            const int n = nt * 16 + ln;
            const float bias = bp3f[n];
            #pragma unroll
            for (int r = 0; r < 4; ++r) {
                const int m = wave * 16 + quad * 4 + r;
                h3[m * S3 + n] = acc[nt][r] + bias;
            }
        }
    }
    __syncthreads();

    // ---- scatter (ids sorted -> run-length compression) ----
    if (t < 64) {
        int cur = sid[0];
        float local = h3[t];
        for (int e = 1; e < E; ++e) {
            const int id = sid[e];
            const float v = h3[e * S3 + t];
            if (id == cur) local += v;
            else { atomicAdd(&agg[(long)cur * 64 + t], local); cur = id; local = v; }
        }
        atomicAdd(&agg[(long)cur * 64 + t], local);
    } else if (t < 66) {
        const int f = t - 64;
        int cur = sid[0];
        float local = cb[0][f];
        for (int e = 1; e < E; ++e) {
            const int id = sid[e];
            const float v = cb[e][f];
            if (id == cur) local += v;
            else { atomicAdd(&bar[cur * 2 + f], local); cur = id; local = v; }
        }
        atomicAdd(&bar[cur * 2 + f], local);
    }
}

// ---------------------------------------------------------------------------
// Stage 2: per-agent MLP 64 -> 256 -> 256 -> 2, plus barrier term.
// ---------------------------------------------------------------------------
__global__ __launch_bounds__(256) void agent_mlp_kernel(
    const float* __restrict__ agg, const float* __restrict__ bar,
    const void* __restrict__ Wr1, const void* __restrict__ br1,
    const void* __restrict__ Wr2, const void* __restrict__ br2,
    const void* __restrict__ Wr3, const void* __restrict__ br3,
    void* __restrict__ out, const int* __restrict__ flag)
{
    __shared__ __align__(16) float a[64];
    __shared__ __align__(16) float r1[256];
    __shared__ float part[2][4];

    const int t = threadIdx.x;
    const int agent = blockIdx.x;
    const int f32 = *flag;

    if (t < 64) a[t] = agg[(long)agent * 64 + t];
    __syncthreads();

    float acc = ld(br1, t, f32);
    #pragma unroll
    for (int k = 0; k < 64; ++k) acc = fmaf(a[k], ld(Wr1, (long)k * 256 + t, f32), acc);
    r1[t] = acc > 0.f ? acc : 0.f;
    __syncthreads();

    float acc2 = ld(br2, t, f32);
    for (int k = 0; k < 256; k += 4) {
        const float4 h = *(const float4*)&r1[k];
        acc2 = fmaf(h.x, ld(Wr2, (long)(k + 0) * 256 + t, f32),
               fmaf(h.y, ld(Wr2, (long)(k + 1) * 256 + t, f32),
               fmaf(h.z, ld(Wr2, (long)(k + 2) * 256 + t, f32),
               fmaf(h.w, ld(Wr2, (long)(k + 3) * 256 + t, f32), acc2))));
    }
    const float r2v = acc2 > 0.f ? acc2 : 0.f;

    float v0 = r2v * ld(Wr3, (long)t * 2 + 0, f32);
    float v1 = r2v * ld(Wr3, (long)t * 2 + 1, f32);
    #pragma unroll
    for (int off = 32; off > 0; off >>= 1) {
        v0 += __shfl_down(v0, off, 64);
        v1 += __shfl_down(v1, off, 64);
    }
    if ((t & 63) == 0) { part[0][t >> 6] = v0; part[1][t >> 6] = v1; }
    __syncthreads();
    if (t < 2) {
        const float s = part[t][0] + part[t][1] + part[t][2] + part[t][3]
                      + ld(br3, t, f32) + bar[agent * 2 + t];
        if (f32) ((float*)out)[agent * 2 + t] = s;
        else     ((bf16*)out)[agent * 2 + t] = __float2bfloat16(s);
    }
}

extern "C" void kernel_launch(void* const* d_in, const int* in_sizes, int n_in,
                              void* d_out, int out_size, void* d_ws, size_t ws_size,
                              hipStream_t stream)
{
    (void)in_sizes; (void)n_in; (void)out_size;

    const void* ef  = d_in[0];
    const int*  ids = (const int*)d_in[1];
    const void* Wp1 = d_in[2];
    const void* bp1 = d_in[3];
    const void* Wp2 = d_in[4];
    const void* bp2 = d_in[5];
    const void* Wp3 = d_in[6];
    const void* bp3 = d_in[7];
    const void* Wr1 = d_in[8];
    const void* br1 = d_in[9];
    const void* Wr2 = d_in[10];
    const void* br2 = d_in[11];
    const void* Wr3 = d_in[12];
    const void* br3 = d_in[13];

    // ws layout (16B-aligned chunks)
    char* p = (char*)d_ws;
    int*   flag = (int*)p;                         p += 256;
    float* agg  = (float*)p;                       p += (size_t)NA * 64 * 4;
    float* bar  = (float*)p;                       p += (size_t)NA * 2 * 4;
    float* Wp1f = (float*)p;                       p += 1024 * 4;
    float* bp1f = (float*)p;                       p += 256 * 4;
    float* bp2f = (float*)p;                       p += 256 * 4;
    float* bp3f = (float*)p;                       p += 64 * 4;
    short* Wp2T = (short*)p;                       p += 65536 * 2;
    short* Wp3T = (short*)p;                       p += 16384 * 2;
    const size_t required = (size_t)(p - (char*)d_ws);
    if (ws_size < required) return;  // signature: output stays zero (absmax ~26)

    detect_dtype_kernel<<<1, 64, 0, stream>>>((const unsigned short*)Wp2, flag);
    hipMemsetAsync(agg, 0, ((size_t)NA * 64 + (size_t)NA * 2) * 4, stream);
    prep_weights_kernel<<<64, 256, 0, stream>>>(Wp1, bp1, Wp2, bp2, Wp3, bp3,
                                                Wp1f, bp1f, bp2f, bp3f, Wp2T, Wp3T, flag);
    edge_mlp_kernel<<<NE / E, 256, 0, stream>>>(ef, ids, Wp1f, bp1f, Wp2T, bp2f,
                                                Wp3T, bp3f, agg, bar, flag);
    agent_mlp_kernel<<<NA, 256, 0, stream>>>(agg, bar, Wr1, br1, Wr2, br2, Wr3, br3,
                                             d_out, flag);
}

// Round 4
// 384.280 us; speedup vs baseline: 5.7348x; 2.0292x over previous
//
#include <hip/hip_runtime.h>
#include <hip/hip_bf16.h>

typedef __hip_bfloat16 bf16;
typedef __attribute__((ext_vector_type(8))) short short8;   // MFMA A/B frag (8 bf16)
typedef __attribute__((ext_vector_type(4))) float floatx4;  // MFMA C/D frag

#define NE 524288
#define NA 16384
#define E  64        // edges/agents per block
#define S1 260       // LDS act row stride (shorts): dword stride 130 == 2 mod 32
#define SH3 65       // h3 row stride (floats)

__device__ __forceinline__ float ld(const void* p, long i, int f32) {
    return f32 ? ((const float*)p)[i] : __bfloat162float(((const bf16*)p)[i]);
}
__device__ __forceinline__ short f2bs(float f) {
    bf16 h = __float2bfloat16(f);
    return *(short*)&h;
}
__device__ __forceinline__ float bs2f(short s) {
    union { unsigned u; float f; } c;
    c.u = ((unsigned)(unsigned short)s) << 16;
    return c.f;
}

// ---------------------------------------------------------------------------
// Dtype detector (flag=1 -> tensors are float32).
// ---------------------------------------------------------------------------
__global__ void detect_dtype_kernel(const unsigned short* __restrict__ w,
                                    int* __restrict__ flag) {
    const int t = threadIdx.x;
    int bad = 0;
    for (int i = t; i < 1024; i += 64) {
        const int e = (w[i] >> 7) & 0xFF;
        if (e >= 131) bad = 1;
    }
    const unsigned long long m = __ballot(bad);
    if (t == 0) *flag = (m != 0ull) ? 1 : 0;
}

// ---------------------------------------------------------------------------
// Weight prep: bf16-ize + transpose all GEMM weights to n-major [n][k];
// Wp1Tp zero-padded to K=32. Biases + Wr3 to f32.
// ---------------------------------------------------------------------------
__global__ void prep_weights_kernel(
    const void* __restrict__ Wp1, const void* __restrict__ bp1,
    const void* __restrict__ Wp2, const void* __restrict__ bp2,
    const void* __restrict__ Wp3, const void* __restrict__ bp3,
    const void* __restrict__ Wr1, const void* __restrict__ br1,
    const void* __restrict__ Wr2, const void* __restrict__ br2,
    const void* __restrict__ Wr3, const void* __restrict__ br3,
    short* __restrict__ Wp1Tp, short* __restrict__ Wp2T, short* __restrict__ Wp3T,
    short* __restrict__ Wr1T,  short* __restrict__ Wr2T,
    float* __restrict__ bp1f, float* __restrict__ bp2f, float* __restrict__ bp3f,
    float* __restrict__ br1f, float* __restrict__ br2f,
    float* __restrict__ Wr3f, float* __restrict__ br3f,
    const int* __restrict__ flag)
{
    const int f32 = *flag;
    const int stride = gridDim.x * blockDim.x;
    for (int i = blockIdx.x * blockDim.x + threadIdx.x; i < 173634; i += stride) {
        if (i < 65536) {                       // Wp2T[n][k] = Wp2[k][n]
            const int n = i >> 8, k = i & 255;
            Wp2T[i] = f2bs(ld(Wp2, (long)k * 256 + n, f32));
        } else if (i < 81920) {                // Wp3T[n][k] = Wp3[k][n]
            const int j = i - 65536, n = j >> 8, k = j & 255;
            Wp3T[j] = f2bs(ld(Wp3, (long)k * 64 + n, f32));
        } else if (i < 90112) {                // Wp1Tp[n][k<32], zero-pad k>=4
            const int j = i - 81920, n = j >> 5, k = j & 31;
            Wp1Tp[j] = (k < 4) ? f2bs(ld(Wp1, (long)k * 256 + n, f32)) : (short)0;
        } else if (i < 106496) {               // Wr1T[n][k=64]
            const int j = i - 90112, n = j >> 6, k = j & 63;
            Wr1T[j] = f2bs(ld(Wr1, (long)k * 256 + n, f32));
        } else if (i < 172032) {               // Wr2T[n][k=256]
            const int j = i - 106496, n = j >> 8, k = j & 255;
            Wr2T[j] = f2bs(ld(Wr2, (long)k * 256 + n, f32));
        } else if (i < 172288) { bp1f[i - 172032] = ld(bp1, i - 172032, f32); }
        else if (i < 172544) { bp2f[i - 172288] = ld(bp2, i - 172288, f32); }
        else if (i < 172608) { bp3f[i - 172544] = ld(bp3, i - 172544, f32); }
        else if (i < 172864) { br1f[i - 172608] = ld(br1, i - 172608, f32); }
        else if (i < 173120) { br2f[i - 172864] = ld(br2, i - 172864, f32); }
        else if (i < 173632) { Wr3f[i - 173120] = ld(Wr3, i - 173120, f32); }
        else                 { br3f[i - 173632] = ld(br3, i - 173632, f32); }
    }
}

// ---------------------------------------------------------------------------
// Edge MLP, all-MFMA. 64 edges/block, 4 waves, single LDS act buffer.
// ---------------------------------------------------------------------------
__global__ __launch_bounds__(256, 3) void edge_mlp_kernel(
    const void* __restrict__ ef, const int* __restrict__ ids,
    const short* __restrict__ Wp1Tp, const float* __restrict__ bp1f,
    const short* __restrict__ Wp2T, const float* __restrict__ bp2f,
    const short* __restrict__ Wp3T, const float* __restrict__ bp3f,
    float* __restrict__ agg, float* __restrict__ bar,
    const int* __restrict__ flag)
{
    __shared__ __align__(16) short hs[E * S1];     // h1, then h2 (33.3 KB)
    __shared__ __align__(16) float h3f[E * SH3];   // 16.6 KB
    __shared__ float cb[E][2];
    __shared__ int   sid[E];

    const int t = threadIdx.x;
    const long e0 = (long)blockIdx.x * E;
    const int f32 = *flag;
    const int wave = t >> 6, lane = t & 63, quad = lane >> 4, ln = lane & 15;
    const int nb = wave * 64;

    if (t < E) {
        sid[t] = ids[e0 + t];
        const float px = ld(ef, (e0 + t) * 4 + 0, f32);
        const float py = ld(ef, (e0 + t) * 4 + 1, f32);
        const float d = sqrtf(px * px + py * py);
        const float inv = 1.0f / (d * (d - 0.18f));
        cb[t][0] = -px * inv;
        cb[t][1] = -py * inv;
    }

    // ---- layer 1 (MFMA, K=32 zero-padded): h1 = relu(x @ Wp1 + bp1) ----
    {
        short8 a[4];
        #pragma unroll
        for (int mt = 0; mt < 4; ++mt) {
            short8 v = {};
            if (quad == 0) {
                const long e = e0 + mt * 16 + ln;
                if (f32) {
                    const float4 x = ((const float4*)ef)[e];
                    v[0] = f2bs(x.x); v[1] = f2bs(x.y); v[2] = f2bs(x.z); v[3] = f2bs(x.w);
                } else {
                    const int2 x = ((const int2*)ef)[e];
                    v[0] = (short)(x.x & 0xffff); v[1] = (short)((unsigned)x.x >> 16);
                    v[2] = (short)(x.y & 0xffff); v[3] = (short)((unsigned)x.y >> 16);
                }
            }
            a[mt] = v;
        }
        floatx4 acc[4][4] = {};
        #pragma unroll
        for (int nt = 0; nt < 4; ++nt) {
            const short8 b = *(const short8*)&Wp1Tp[(nb + nt * 16 + ln) * 32 + quad * 8];
            #pragma unroll
            for (int mt = 0; mt < 4; ++mt)
                acc[mt][nt] = __builtin_amdgcn_mfma_f32_16x16x32_bf16(a[mt], b, acc[mt][nt], 0, 0, 0);
        }
        #pragma unroll
        for (int nt = 0; nt < 4; ++nt) {
            const int n = nb + nt * 16 + ln;
            const float bias = bp1f[n];
            #pragma unroll
            for (int mt = 0; mt < 4; ++mt)
                #pragma unroll
                for (int r = 0; r < 4; ++r) {
                    const int m = mt * 16 + quad * 4 + r;
                    const float v = acc[mt][nt][r] + bias;
                    hs[m * S1 + n] = f2bs(v > 0.f ? v : 0.f);
                }
        }
    }
    __syncthreads();

    // ---- layer 2 (MFMA): h2 = relu(h1 @ Wp2 + bp2), B prefetched ----
    {
        floatx4 acc[4][4] = {};
        short8 bcur[4], bnxt[4];
        #pragma unroll
        for (int nt = 0; nt < 4; ++nt)
            bcur[nt] = *(const short8*)&Wp2T[(nb + nt * 16 + ln) * 256 + quad * 8];
        #pragma unroll
        for (int ks = 0; ks < 8; ++ks) {
            if (ks < 7) {
                #pragma unroll
                for (int nt = 0; nt < 4; ++nt)
                    bnxt[nt] = *(const short8*)&Wp2T[(nb + nt * 16 + ln) * 256 + (ks + 1) * 32 + quad * 8];
            }
            short8 a[4];
            #pragma unroll
            for (int mt = 0; mt < 4; ++mt)
                a[mt] = *(const short8*)&hs[(mt * 16 + ln) * S1 + ks * 32 + quad * 8];
            #pragma unroll
            for (int mt = 0; mt < 4; ++mt)
                #pragma unroll
                for (int nt = 0; nt < 4; ++nt)
                    acc[mt][nt] = __builtin_amdgcn_mfma_f32_16x16x32_bf16(a[mt], bcur[nt], acc[mt][nt], 0, 0, 0);
            #pragma unroll
            for (int nt = 0; nt < 4; ++nt) bcur[nt] = bnxt[nt];
        }
        __syncthreads();   // all h1 reads complete before overwrite
        #pragma unroll
        for (int nt = 0; nt < 4; ++nt) {
            const int n = nb + nt * 16 + ln;
            const float bias = bp2f[n];
            #pragma unroll
            for (int mt = 0; mt < 4; ++mt)
                #pragma unroll
                for (int r = 0; r < 4; ++r) {
                    const int m = mt * 16 + quad * 4 + r;
                    const float v = acc[mt][nt][r] + bias;
                    hs[m * S1 + n] = f2bs(v > 0.f ? v : 0.f);
                }
        }
    }
    __syncthreads();

    // ---- layer 3 (MFMA): h3 = h2 @ Wp3 + bp3 (per-wave 16-edge M-tile) ----
    {
        floatx4 acc[4] = {};
        const int mrow = wave * 16 + ln;
        #pragma unroll 2
        for (int ks = 0; ks < 8; ++ks) {
            const short8 a = *(const short8*)&hs[mrow * S1 + ks * 32 + quad * 8];
            #pragma unroll
            for (int nt = 0; nt < 4; ++nt) {
                const short8 b = *(const short8*)&Wp3T[(nt * 16 + ln) * 256 + ks * 32 + quad * 8];
                acc[nt] = __builtin_amdgcn_mfma_f32_16x16x32_bf16(a, b, acc[nt], 0, 0, 0);
            }
        }
        #pragma unroll
        for (int nt = 0; nt < 4; ++nt) {
            const int n = nt * 16 + ln;
            const float bias = bp3f[n];
            #pragma unroll
            for (int r = 0; r < 4; ++r) {
                const int m = wave * 16 + quad * 4 + r;
                h3f[m * SH3 + n] = acc[nt][r] + bias;
            }
        }
    }
    __syncthreads();

    // ---- scatter: each wave handles its own 16-edge window (ids sorted) ----
    {
        const int w0 = wave * 16;
        const int f = lane;                     // feature 0..63
        int cur = sid[w0];
        float local = h3f[w0 * SH3 + f];
        #pragma unroll
        for (int e = 1; e < 16; ++e) {
            const int id = sid[w0 + e];
            const float v = h3f[(w0 + e) * SH3 + f];
            if (id == cur) local += v;
            else { atomicAdd(&agg[(long)cur * 64 + f], local); cur = id; local = v; }
        }
        atomicAdd(&agg[(long)cur * 64 + f], local);

        if (lane < 2) {
            int c2 = sid[w0];
            float l2 = cb[w0][lane];
            #pragma unroll
            for (int e = 1; e < 16; ++e) {
                const int id = sid[w0 + e];
                const float v = cb[w0 + e][lane];
                if (id == c2) l2 += v;
                else { atomicAdd(&bar[c2 * 2 + lane], l2); c2 = id; l2 = v; }
            }
            atomicAdd(&bar[c2 * 2 + lane], l2);
        }
    }
}

// ---------------------------------------------------------------------------
// Agent MLP, all-MFMA. 64 agents/block, 256 blocks.
// ---------------------------------------------------------------------------
__global__ __launch_bounds__(256, 2) void agent_mlp_kernel(
    const float* __restrict__ agg, const float* __restrict__ bar,
    const short* __restrict__ Wr1T, const float* __restrict__ br1f,
    const short* __restrict__ Wr2T, const float* __restrict__ br2f,
    const float* __restrict__ Wr3f, const float* __restrict__ br3f,
    void* __restrict__ out, const int* __restrict__ flag)
{
    __shared__ __align__(16) short ha[64 * 68];    // bf16 agg (8.7 KB)
    __shared__ __align__(16) short hs[64 * S1];    // r1, then r2 (33.3 KB)
    __shared__ float part[4][64][2];

    const int t = threadIdx.x;
    const int a0 = blockIdx.x * 64;
    const int f32 = *flag;
    const int wave = t >> 6, lane = t & 63, quad = lane >> 4, ln = lane & 15;
    const int nb = wave * 64;

    #pragma unroll
    for (int i = 0; i < 16; ++i) {
        const int idx = t + i * 256;               // 0..4095
        ha[(idx >> 6) * 68 + (idx & 63)] = f2bs(agg[(long)a0 * 64 + idx]);
    }
    __syncthreads();

    // ---- r1 = relu(a @ Wr1 + br1), K=64 ----
    {
        floatx4 acc[4][4] = {};
        #pragma unroll
        for (int ks = 0; ks < 2; ++ks) {
            short8 a[4], b[4];
            #pragma unroll
            for (int mt = 0; mt < 4; ++mt)
                a[mt] = *(const short8*)&ha[(mt * 16 + ln) * 68 + ks * 32 + quad * 8];
            #pragma unroll
            for (int nt = 0; nt < 4; ++nt)
                b[nt] = *(const short8*)&Wr1T[(nb + nt * 16 + ln) * 64 + ks * 32 + quad * 8];
            #pragma unroll
            for (int mt = 0; mt < 4; ++mt)
                #pragma unroll
                for (int nt = 0; nt < 4; ++nt)
                    acc[mt][nt] = __builtin_amdgcn_mfma_f32_16x16x32_bf16(a[mt], b[nt], acc[mt][nt], 0, 0, 0);
        }
        #pragma unroll
        for (int nt = 0; nt < 4; ++nt) {
            const int n = nb + nt * 16 + ln;
            const float bias = br1f[n];
            #pragma unroll
            for (int mt = 0; mt < 4; ++mt)
                #pragma unroll
                for (int r = 0; r < 4; ++r) {
                    const int m = mt * 16 + quad * 4 + r;
                    const float v = acc[mt][nt][r] + bias;
                    hs[m * S1 + n] = f2bs(v > 0.f ? v : 0.f);
                }
        }
    }
    __syncthreads();

    // ---- r2 = relu(r1 @ Wr2 + br2), K=256, single-buffer ----
    {
        floatx4 acc[4][4] = {};
        short8 bcur[4], bnxt[4];
        #pragma unroll
        for (int nt = 0; nt < 4; ++nt)
            bcur[nt] = *(const short8*)&Wr2T[(nb + nt * 16 + ln) * 256 + quad * 8];
        #pragma unroll
        for (int ks = 0; ks < 8; ++ks) {
            if (ks < 7) {
                #pragma unroll
                for (int nt = 0; nt < 4; ++nt)
                    bnxt[nt] = *(const short8*)&Wr2T[(nb + nt * 16 + ln) * 256 + (ks + 1) * 32 + quad * 8];
            }
            short8 a[4];
            #pragma unroll
            for (int mt = 0; mt < 4; ++mt)
                a[mt] = *(const short8*)&hs[(mt * 16 + ln) * S1 + ks * 32 + quad * 8];
            #pragma unroll
            for (int mt = 0; mt < 4; ++mt)
                #pragma unroll
                for (int nt = 0; nt < 4; ++nt)
                    acc[mt][nt] = __builtin_amdgcn_mfma_f32_16x16x32_bf16(a[mt], bcur[nt], acc[mt][nt], 0, 0, 0);
            #pragma unroll
            for (int nt = 0; nt < 4; ++nt) bcur[nt] = bnxt[nt];
        }
        __syncthreads();
        #pragma unroll
        for (int nt = 0; nt < 4; ++nt) {
            const int n = nb + nt * 16 + ln;
            const float bias = br2f[n];
            #pragma unroll
            for (int mt = 0; mt < 4; ++mt)
                #pragma unroll
                for (int r = 0; r < 4; ++r) {
                    const int m = mt * 16 + quad * 4 + r;
                    const float v = acc[mt][nt][r] + bias;
                    hs[m * S1 + n] = f2bs(v > 0.f ? v : 0.f);
                }
        }
    }
    __syncthreads();

    // ---- out = r2 @ Wr3 + br3 + bar (N=2, VALU, 4-way K-split) ----
    {
        const int m = t & 63;
        const int p = t >> 6;
        float v0 = 0.f, v1 = 0.f;
        #pragma unroll
        for (int kk = 0; kk < 8; ++kk) {
            const int k0 = p * 64 + kk * 8;
            const short8 h = *(const short8*)&hs[m * S1 + k0];
            #pragma unroll
            for (int j = 0; j < 8; ++j) {
                const float hv = bs2f(h[j]);
                v0 = fmaf(hv, Wr3f[(k0 + j) * 2 + 0], v0);
                v1 = fmaf(hv, Wr3f[(k0 + j) * 2 + 1], v1);
            }
        }
        part[p][m][0] = v0;
        part[p][m][1] = v1;
    }
    __syncthreads();
    if (t < 128) {
        const int m = t >> 1, o = t & 1;
        const float s = part[0][m][o] + part[1][m][o] + part[2][m][o] + part[3][m][o]
                      + br3f[o] + bar[(long)(a0 + m) * 2 + o];
        if (f32) ((float*)out)[(a0 + m) * 2 + o] = s;
        else     ((bf16*)out)[(a0 + m) * 2 + o] = __float2bfloat16(s);
    }
}

extern "C" void kernel_launch(void* const* d_in, const int* in_sizes, int n_in,
                              void* d_out, int out_size, void* d_ws, size_t ws_size,
                              hipStream_t stream)
{
    (void)in_sizes; (void)n_in; (void)out_size;

    const void* ef  = d_in[0];
    const int*  ids = (const int*)d_in[1];

    char* p = (char*)d_ws;
    int*   flag  = (int*)p;        p += 256;
    float* agg   = (float*)p;      p += (size_t)NA * 64 * 4;
    float* bar   = (float*)p;      p += (size_t)NA * 2 * 4;
    short* Wp1Tp = (short*)p;      p += 8192 * 2;
    short* Wp2T  = (short*)p;      p += 65536 * 2;
    short* Wp3T  = (short*)p;      p += 16384 * 2;
    short* Wr1T  = (short*)p;      p += 16384 * 2;
    short* Wr2T  = (short*)p;      p += 65536 * 2;
    float* bp1f  = (float*)p;      p += 256 * 4;
    float* bp2f  = (float*)p;      p += 256 * 4;
    float* bp3f  = (float*)p;      p += 64 * 4;
    float* br1f  = (float*)p;      p += 256 * 4;
    float* br2f  = (float*)p;      p += 256 * 4;
    float* Wr3f  = (float*)p;      p += 512 * 4;
    float* br3f  = (float*)p;      p += 256;
    const size_t required = (size_t)(p - (char*)d_ws);
    if (ws_size < required) return;  // signature: output stays zero (absmax ~26)

    detect_dtype_kernel<<<1, 64, 0, stream>>>((const unsigned short*)d_in[4], flag);
    hipMemsetAsync(agg, 0, ((size_t)NA * 64 + (size_t)NA * 2) * 4, stream);
    prep_weights_kernel<<<64, 256, 0, stream>>>(
        d_in[2], d_in[3], d_in[4], d_in[5], d_in[6], d_in[7],
        d_in[8], d_in[9], d_in[10], d_in[11], d_in[12], d_in[13],
        Wp1Tp, Wp2T, Wp3T, Wr1T, Wr2T,
        bp1f, bp2f, bp3f, br1f, br2f, Wr3f, br3f, flag);
    edge_mlp_kernel<<<NE / E, 256, 0, stream>>>(
        ef, ids, Wp1Tp, bp1f, Wp2T, bp2f, Wp3T, bp3f, agg, bar, flag);
    agent_mlp_kernel<<<NA / 64, 256, 0, stream>>>(
        agg, bar, Wr1T, br1f, Wr2T, br2f, Wr3f, br3f, d_out, flag);
}

// Round 5
// 369.341 us; speedup vs baseline: 5.9668x; 1.0404x over previous
//
#include <hip/hip_runtime.h>
#include <hip/hip_bf16.h>

typedef __hip_bfloat16 bf16;
typedef __attribute__((ext_vector_type(8))) short short8;   // MFMA A/B frag (8 bf16)
typedef __attribute__((ext_vector_type(4))) float floatx4;  // MFMA C/D frag
typedef __attribute__((ext_vector_type(4))) short s16x4;

#define NE 524288
#define NA 16384
#define E  64        // edges per block (edge kernel)
#define AG 32        // agents per block (agent kernel)
#define S1 260       // LDS act row stride (shorts): dword stride 130 == 2 mod 32
#define SH3 130      // h3 overlay row stride (floats) == S1/2

__device__ __forceinline__ float ld(const void* p, long i, int f32) {
    return f32 ? ((const float*)p)[i] : __bfloat162float(((const bf16*)p)[i]);
}
__device__ __forceinline__ short f2bs(float f) {
    bf16 h = __float2bfloat16(f);
    return *(short*)&h;
}
__device__ __forceinline__ float bs2f(short s) {
    union { unsigned u; float f; } c;
    c.u = ((unsigned)(unsigned short)s) << 16;
    return c.f;
}

// ---------------------------------------------------------------------------
// Weight prep (dtype detector fused in): bf16-ize + transpose GEMM weights to
// n-major [n][k]; Wp1Tp zero-padded to K=32. Biases + Wr3 to f32.
// ---------------------------------------------------------------------------
__global__ void prep_weights_kernel(
    const void* __restrict__ Wp1, const void* __restrict__ bp1,
    const void* __restrict__ Wp2, const void* __restrict__ bp2,
    const void* __restrict__ Wp3, const void* __restrict__ bp3,
    const void* __restrict__ Wr1, const void* __restrict__ br1,
    const void* __restrict__ Wr2, const void* __restrict__ br2,
    const void* __restrict__ Wr3, const void* __restrict__ br3,
    short* __restrict__ Wp1Tp, short* __restrict__ Wp2T, short* __restrict__ Wp3T,
    short* __restrict__ Wr1T,  short* __restrict__ Wr2T,
    float* __restrict__ bp1f, float* __restrict__ bp2f, float* __restrict__ bp3f,
    float* __restrict__ br1f, float* __restrict__ br2f,
    float* __restrict__ Wr3f, float* __restrict__ br3f,
    int* __restrict__ flag)
{
    __shared__ int sflag;
    // per-block dtype detection on Wp2's first 1024 shorts (wave 0)
    if (threadIdx.x < 64) {
        const unsigned short* w = (const unsigned short*)Wp2;
        int bad = 0;
        for (int i = threadIdx.x; i < 1024; i += 64) {
            const int e = (w[i] >> 7) & 0xFF;
            if (e >= 131) bad = 1;                // |v|>=16 / inf / nan -> f32 bits
        }
        const unsigned long long m = __ballot(bad);
        if (threadIdx.x == 0) {
            sflag = (m != 0ull) ? 1 : 0;
            if (blockIdx.x == 0) *flag = sflag;   // publish for edge/agent kernels
        }
    }
    __syncthreads();
    const int f32 = sflag;

    const int stride = gridDim.x * blockDim.x;
    for (int i = blockIdx.x * blockDim.x + threadIdx.x; i < 173634; i += stride) {
        if (i < 65536) {                       // Wp2T[n][k] = Wp2[k][n]
            const int n = i >> 8, k = i & 255;
            Wp2T[i] = f2bs(ld(Wp2, (long)k * 256 + n, f32));
        } else if (i < 81920) {                // Wp3T[n][k] = Wp3[k][n]
            const int j = i - 65536, n = j >> 8, k = j & 255;
            Wp3T[j] = f2bs(ld(Wp3, (long)k * 64 + n, f32));
        } else if (i < 90112) {                // Wp1Tp[n][k<32], zero-pad k>=4
            const int j = i - 81920, n = j >> 5, k = j & 31;
            Wp1Tp[j] = (k < 4) ? f2bs(ld(Wp1, (long)k * 256 + n, f32)) : (short)0;
        } else if (i < 106496) {               // Wr1T[n][k=64]
            const int j = i - 90112, n = j >> 6, k = j & 63;
            Wr1T[j] = f2bs(ld(Wr1, (long)k * 256 + n, f32));
        } else if (i < 172032) {               // Wr2T[n][k=256]
            const int j = i - 106496, n = j >> 8, k = j & 255;
            Wr2T[j] = f2bs(ld(Wr2, (long)k * 256 + n, f32));
        } else if (i < 172288) { bp1f[i - 172032] = ld(bp1, i - 172032, f32); }
        else if (i < 172544) { bp2f[i - 172288] = ld(bp2, i - 172288, f32); }
        else if (i < 172608) { bp3f[i - 172544] = ld(bp3, i - 172544, f32); }
        else if (i < 172864) { br1f[i - 172608] = ld(br1, i - 172608, f32); }
        else if (i < 173120) { br2f[i - 172864] = ld(br2, i - 172864, f32); }
        else if (i < 173632) { Wr3f[i - 173120] = ld(Wr3, i - 173120, f32); }
        else                 { br3f[i - 173632] = ld(br3, i - 173632, f32); }
    }
}

// ---------------------------------------------------------------------------
// Edge MLP, all-MFMA, 64 edges/block, 4 waves. Single LDS buffer: h1 -> h2 ->
// (overlay) h3. h3 row m reuses the first 260B of hs row m, and in L3 each
// wave touches ONLY its own 16 rows => no barrier between L3 and scatter.
// ---------------------------------------------------------------------------
__global__ __launch_bounds__(256, 4) void edge_mlp_kernel(
    const void* __restrict__ ef, const int* __restrict__ ids,
    const short* __restrict__ Wp1Tp, const float* __restrict__ bp1f,
    const short* __restrict__ Wp2T, const float* __restrict__ bp2f,
    const short* __restrict__ Wp3T, const float* __restrict__ bp3f,
    float* __restrict__ agg, float* __restrict__ bar,
    const int* __restrict__ flag)
{
    __shared__ __align__(16) short hs[E * S1];     // 33.3 KB: h1, h2, then h3 overlay
    __shared__ float cb[E][2];
    __shared__ int   sid[E];
    float* h3f = (float*)hs;                       // row m at float offset m*SH3

    const int t = threadIdx.x;
    const long e0 = (long)blockIdx.x * E;
    const int f32 = *flag;
    const int wave = t >> 6, lane = t & 63, quad = lane >> 4, ln = lane & 15;
    const int nb = wave * 64;

    if (t < E) {
        sid[t] = ids[e0 + t];
        const float px = ld(ef, (e0 + t) * 4 + 0, f32);
        const float py = ld(ef, (e0 + t) * 4 + 1, f32);
        const float d = sqrtf(px * px + py * py);
        const float inv = 1.0f / (d * (d - 0.18f));
        cb[t][0] = -px * inv;
        cb[t][1] = -py * inv;
    }

    // ---- layer 1 (MFMA, K=32 zero-padded): h1 = relu(x @ Wp1 + bp1) ----
    {
        short8 a[4];
        #pragma unroll
        for (int mt = 0; mt < 4; ++mt) {
            short8 v = {};
            if (quad == 0) {
                const long e = e0 + mt * 16 + ln;
                if (f32) {
                    const float4 x = ((const float4*)ef)[e];
                    v[0] = f2bs(x.x); v[1] = f2bs(x.y); v[2] = f2bs(x.z); v[3] = f2bs(x.w);
                } else {
                    const int2 x = ((const int2*)ef)[e];
                    v[0] = (short)(x.x & 0xffff); v[1] = (short)((unsigned)x.x >> 16);
                    v[2] = (short)(x.y & 0xffff); v[3] = (short)((unsigned)x.y >> 16);
                }
            }
            a[mt] = v;
        }
        floatx4 acc[4][4] = {};
        #pragma unroll
        for (int nt = 0; nt < 4; ++nt) {
            const short8 b = *(const short8*)&Wp1Tp[(nb + nt * 16 + ln) * 32 + quad * 8];
            #pragma unroll
            for (int mt = 0; mt < 4; ++mt)
                acc[mt][nt] = __builtin_amdgcn_mfma_f32_16x16x32_bf16(a[mt], b, acc[mt][nt], 0, 0, 0);
        }
        #pragma unroll
        for (int nt = 0; nt < 4; ++nt) {
            const int n = nb + nt * 16 + ln;
            const float bias = bp1f[n];
            #pragma unroll
            for (int mt = 0; mt < 4; ++mt)
                #pragma unroll
                for (int r = 0; r < 4; ++r) {
                    const int m = mt * 16 + quad * 4 + r;
                    const float v = acc[mt][nt][r] + bias;
                    hs[m * S1 + n] = f2bs(v > 0.f ? v : 0.f);
                }
        }
    }
    __syncthreads();

    // ---- layer 2 (MFMA): h2 = relu(h1 @ Wp2 + bp2), B prefetched ----
    {
        floatx4 acc[4][4] = {};
        short8 bcur[4], bnxt[4];
        #pragma unroll
        for (int nt = 0; nt < 4; ++nt)
            bcur[nt] = *(const short8*)&Wp2T[(nb + nt * 16 + ln) * 256 + quad * 8];
        #pragma unroll
        for (int ks = 0; ks < 8; ++ks) {
            if (ks < 7) {
                #pragma unroll
                for (int nt = 0; nt < 4; ++nt)
                    bnxt[nt] = *(const short8*)&Wp2T[(nb + nt * 16 + ln) * 256 + (ks + 1) * 32 + quad * 8];
            }
            short8 a[4];
            #pragma unroll
            for (int mt = 0; mt < 4; ++mt)
                a[mt] = *(const short8*)&hs[(mt * 16 + ln) * S1 + ks * 32 + quad * 8];
            #pragma unroll
            for (int mt = 0; mt < 4; ++mt)
                #pragma unroll
                for (int nt = 0; nt < 4; ++nt)
                    acc[mt][nt] = __builtin_amdgcn_mfma_f32_16x16x32_bf16(a[mt], bcur[nt], acc[mt][nt], 0, 0, 0);
            #pragma unroll
            for (int nt = 0; nt < 4; ++nt) bcur[nt] = bnxt[nt];
        }
        __syncthreads();   // all h1 reads complete before overwrite
        #pragma unroll
        for (int nt = 0; nt < 4; ++nt) {
            const int n = nb + nt * 16 + ln;
            const float bias = bp2f[n];
            #pragma unroll
            for (int mt = 0; mt < 4; ++mt)
                #pragma unroll
                for (int r = 0; r < 4; ++r) {
                    const int m = mt * 16 + quad * 4 + r;
                    const float v = acc[mt][nt][r] + bias;
                    hs[m * S1 + n] = f2bs(v > 0.f ? v : 0.f);
                }
        }
    }
    __syncthreads();

    // ---- layer 3 (MFMA): h3 = h2 @ Wp3 + bp3; per-wave 16-edge M-tile ----
    {
        floatx4 acc[4] = {};
        const int mrow = wave * 16 + ln;
        #pragma unroll 2
        for (int ks = 0; ks < 8; ++ks) {
            const short8 a = *(const short8*)&hs[mrow * S1 + ks * 32 + quad * 8];
            #pragma unroll
            for (int nt = 0; nt < 4; ++nt) {
                const short8 b = *(const short8*)&Wp3T[(nt * 16 + ln) * 256 + ks * 32 + quad * 8];
                acc[nt] = __builtin_amdgcn_mfma_f32_16x16x32_bf16(a, b, acc[nt], 0, 0, 0);
            }
        }
        // overlay write: same wave's rows only; DS pipe is in-order per wave
        #pragma unroll
        for (int nt = 0; nt < 4; ++nt) {
            const int n = nt * 16 + ln;
            const float bias = bp3f[n];
            #pragma unroll
            for (int r = 0; r < 4; ++r) {
                const int m = wave * 16 + quad * 4 + r;
                h3f[m * SH3 + n] = acc[nt][r] + bias;
            }
        }
    }
    // no barrier: scatter reads only this wave's rows (+ sid/cb, synced above)

    // ---- scatter: each wave handles its own 16-edge window (ids sorted) ----
    {
        const int w0 = wave * 16;
        const int f = lane;                     // feature 0..63
        int cur = sid[w0];
        float local = h3f[w0 * SH3 + f];
        #pragma unroll
        for (int e = 1; e < 16; ++e) {
            const int id = sid[w0 + e];
            const float v = h3f[(w0 + e) * SH3 + f];
            if (id == cur) local += v;
            else { atomicAdd(&agg[(long)cur * 64 + f], local); cur = id; local = v; }
        }
        atomicAdd(&agg[(long)cur * 64 + f], local);

        if (lane < 2) {
            int c2 = sid[w0];
            float l2 = cb[w0][lane];
            #pragma unroll
            for (int e = 1; e < 16; ++e) {
                const int id = sid[w0 + e];
                const float v = cb[w0 + e][lane];
                if (id == c2) l2 += v;
                else { atomicAdd(&bar[c2 * 2 + lane], l2); c2 = id; l2 = v; }
            }
            atomicAdd(&bar[c2 * 2 + lane], l2);
        }
    }
}

// ---------------------------------------------------------------------------
// Agent MLP, all-MFMA. 32 agents/block, 512 blocks (2 blocks/CU, 2 rounds).
// ---------------------------------------------------------------------------
__global__ __launch_bounds__(256, 2) void agent_mlp_kernel(
    const float* __restrict__ agg, const float* __restrict__ bar,
    const short* __restrict__ Wr1T, const float* __restrict__ br1f,
    const short* __restrict__ Wr2T, const float* __restrict__ br2f,
    const float* __restrict__ Wr3f, const float* __restrict__ br3f,
    void* __restrict__ out, const int* __restrict__ flag)
{
    __shared__ __align__(16) short ha[AG * 68];    // bf16 agg (4.4 KB)
    __shared__ __align__(16) short hs[AG * S1];    // r1, then r2 (16.6 KB)
    __shared__ float part[8][AG][2];

    const int t = threadIdx.x;
    const int a0 = blockIdx.x * AG;
    const int f32 = *flag;
    const int wave = t >> 6, lane = t & 63, quad = lane >> 4, ln = lane & 15;
    const int nb = wave * 64;

    // stage agg -> bf16 LDS (b64 writes: 4 consecutive cols per thread)
    #pragma unroll
    for (int i = 0; i < 2; ++i) {
        const float4 x = ((const float4*)agg)[(long)blockIdx.x * 512 + i * 256 + t];
        const int idx4 = (i * 256 + t) * 4;
        s16x4 v = { f2bs(x.x), f2bs(x.y), f2bs(x.z), f2bs(x.w) };
        *(s16x4*)&ha[(idx4 >> 6) * 68 + (idx4 & 63)] = v;
    }
    __syncthreads();

    // ---- r1 = relu(a @ Wr1 + br1), K=64, M=32 ----
    {
        floatx4 acc[2][4] = {};
        #pragma unroll
        for (int ks = 0; ks < 2; ++ks) {
            short8 a[2], b[4];
            #pragma unroll
            for (int mt = 0; mt < 2; ++mt)
                a[mt] = *(const short8*)&ha[(mt * 16 + ln) * 68 + ks * 32 + quad * 8];
            #pragma unroll
            for (int nt = 0; nt < 4; ++nt)
                b[nt] = *(const short8*)&Wr1T[(nb + nt * 16 + ln) * 64 + ks * 32 + quad * 8];
            #pragma unroll
            for (int mt = 0; mt < 2; ++mt)
                #pragma unroll
                for (int nt = 0; nt < 4; ++nt)
                    acc[mt][nt] = __builtin_amdgcn_mfma_f32_16x16x32_bf16(a[mt], b[nt], acc[mt][nt], 0, 0, 0);
        }
        #pragma unroll
        for (int nt = 0; nt < 4; ++nt) {
            const int n = nb + nt * 16 + ln;
            const float bias = br1f[n];
            #pragma unroll
            for (int mt = 0; mt < 2; ++mt)
                #pragma unroll
                for (int r = 0; r < 4; ++r) {
                    const int m = mt * 16 + quad * 4 + r;
                    const float v = acc[mt][nt][r] + bias;
                    hs[m * S1 + n] = f2bs(v > 0.f ? v : 0.f);
                }
        }
    }
    __syncthreads();

    // ---- r2 = relu(r1 @ Wr2 + br2), K=256, single-buffer ----
    {
        floatx4 acc[2][4] = {};
        short8 bcur[4], bnxt[4];
        #pragma unroll
        for (int nt = 0; nt < 4; ++nt)
            bcur[nt] = *(const short8*)&Wr2T[(nb + nt * 16 + ln) * 256 + quad * 8];
        #pragma unroll
        for (int ks = 0; ks < 8; ++ks) {
            if (ks < 7) {
                #pragma unroll
                for (int nt = 0; nt < 4; ++nt)
                    bnxt[nt] = *(const short8*)&Wr2T[(nb + nt * 16 + ln) * 256 + (ks + 1) * 32 + quad * 8];
            }
            short8 a[2];
            #pragma unroll
            for (int mt = 0; mt < 2; ++mt)
                a[mt] = *(const short8*)&hs[(mt * 16 + ln) * S1 + ks * 32 + quad * 8];
            #pragma unroll
            for (int mt = 0; mt < 2; ++mt)
                #pragma unroll
                for (int nt = 0; nt < 4; ++nt)
                    acc[mt][nt] = __builtin_amdgcn_mfma_f32_16x16x32_bf16(a[mt], bcur[nt], acc[mt][nt], 0, 0, 0);
            #pragma unroll
            for (int nt = 0; nt < 4; ++nt) bcur[nt] = bnxt[nt];
        }
        __syncthreads();
        #pragma unroll
        for (int nt = 0; nt < 4; ++nt) {
            const int n = nb + nt * 16 + ln;
            const float bias = br2f[n];
            #pragma unroll
            for (int mt = 0; mt < 2; ++mt)
                #pragma unroll
                for (int r = 0; r < 4; ++r) {
                    const int m = mt * 16 + quad * 4 + r;
                    const float v = acc[mt][nt][r] + bias;
                    hs[m * S1 + n] = f2bs(v > 0.f ? v : 0.f);
                }
        }
    }
    __syncthreads();

    // ---- out = r2 @ Wr3 + br3 + bar (N=2, VALU, 8-way K-split) ----
    {
        const int m = t & 31;
        const int p = t >> 5;                     // 8 K-partitions of 32
        float v0 = 0.f, v1 = 0.f;
        #pragma unroll
        for (int kk = 0; kk < 4; ++kk) {
            const int k0 = p * 32 + kk * 8;
            const short8 h = *(const short8*)&hs[m * S1 + k0];
            #pragma unroll
            for (int j = 0; j < 8; ++j) {
                const float hv = bs2f(h[j]);
                v0 = fmaf(hv, Wr3f[(k0 + j) * 2 + 0], v0);
                v1 = fmaf(hv, Wr3f[(k0 + j) * 2 + 1], v1);
            }
        }
        part[p][m][0] = v0;
        part[p][m][1] = v1;
    }
    __syncthreads();
    if (t < 64) {
        const int m = t >> 1, o = t & 1;
        float s = br3f[o] + bar[(long)(a0 + m) * 2 + o];
        #pragma unroll
        for (int p = 0; p < 8; ++p) s += part[p][m][o];
        if (f32) ((float*)out)[(a0 + m) * 2 + o] = s;
        else     ((bf16*)out)[(a0 + m) * 2 + o] = __float2bfloat16(s);
    }
}

extern "C" void kernel_launch(void* const* d_in, const int* in_sizes, int n_in,
                              void* d_out, int out_size, void* d_ws, size_t ws_size,
                              hipStream_t stream)
{
    (void)in_sizes; (void)n_in; (void)out_size;

    const void* ef  = d_in[0];
    const int*  ids = (const int*)d_in[1];

    char* p = (char*)d_ws;
    int*   flag  = (int*)p;        p += 256;
    float* agg   = (float*)p;      p += (size_t)NA * 64 * 4;
    float* bar   = (float*)p;      p += (size_t)NA * 2 * 4;
    short* Wp1Tp = (short*)p;      p += 8192 * 2;
    short* Wp2T  = (short*)p;      p += 65536 * 2;
    short* Wp3T  = (short*)p;      p += 16384 * 2;
    short* Wr1T  = (short*)p;      p += 16384 * 2;
    short* Wr2T  = (short*)p;      p += 65536 * 2;
    float* bp1f  = (float*)p;      p += 256 * 4;
    float* bp2f  = (float*)p;      p += 256 * 4;
    float* bp3f  = (float*)p;      p += 64 * 4;
    float* br1f  = (float*)p;      p += 256 * 4;
    float* br2f  = (float*)p;      p += 256 * 4;
    float* Wr3f  = (float*)p;      p += 512 * 4;
    float* br3f  = (float*)p;      p += 256;
    const size_t required = (size_t)(p - (char*)d_ws);
    if (ws_size < required) return;  // signature: output stays zero (absmax ~26)

    hipMemsetAsync(agg, 0, ((size_t)NA * 64 + (size_t)NA * 2) * 4, stream);
    prep_weights_kernel<<<64, 256, 0, stream>>>(
        d_in[2], d_in[3], d_in[4], d_in[5], d_in[6], d_in[7],
        d_in[8], d_in[9], d_in[10], d_in[11], d_in[12], d_in[13],
        Wp1Tp, Wp2T, Wp3T, Wr1T, Wr2T,
        bp1f, bp2f, bp3f, br1f, br2f, Wr3f, br3f, flag);
    edge_mlp_kernel<<<NE / E, 256, 0, stream>>>(
        ef, ids, Wp1Tp, bp1f, Wp2T, bp2f, Wp3T, bp3f, agg, bar, flag);
    agent_mlp_kernel<<<NA / AG, 256, 0, stream>>>(
        agg, bar, Wr1T, br1f, Wr2T, br2f, Wr3f, br3f, d_out, flag);
}

// Round 6
// 356.190 us; speedup vs baseline: 6.1871x; 1.0369x over previous
//
#include <hip/hip_runtime.h>
#include <hip/hip_bf16.h>

typedef __hip_bfloat16 bf16;
typedef __attribute__((ext_vector_type(8))) short short8;   // MFMA A/B frag (8 bf16)
typedef __attribute__((ext_vector_type(4))) float floatx4;  // MFMA C/D frag
typedef __attribute__((ext_vector_type(4))) short s16x4;

#define NE 524288
#define NA 16384
#define E  64        // edges per block (edge kernel)
#define AG 32        // agents per block (agent kernel)
#define S1 260       // LDS act row stride (shorts)
#define SH3 68       // h3 overlay row stride (floats), inside wave's own quarter

__device__ __forceinline__ float ld(const void* p, long i, int f32) {
    return f32 ? ((const float*)p)[i] : __bfloat162float(((const bf16*)p)[i]);
}
__device__ __forceinline__ short f2bs(float f) {
    bf16 h = __float2bfloat16(f);
    return *(short*)&h;
}
__device__ __forceinline__ float bs2f(short s) {
    union { unsigned u; float f; } c;
    c.u = ((unsigned)(unsigned short)s) << 16;
    return c.f;
}
// pack 2 floats -> 2 bf16 in one dword (a = low/even n, b = high/odd n)
__device__ __forceinline__ unsigned pk(float a, float b) {
    return ((unsigned)(unsigned short)f2bs(b) << 16) | (unsigned)(unsigned short)f2bs(a);
}

// ---------------------------------------------------------------------------
// Weight prep (dtype detector fused in): bf16-ize + transpose GEMM weights to
// n-major [n][k]; Wp1Tp zero-padded to K=32. Biases + Wr3 to f32.
// ---------------------------------------------------------------------------
__global__ void prep_weights_kernel(
    const void* __restrict__ Wp1, const void* __restrict__ bp1,
    const void* __restrict__ Wp2, const void* __restrict__ bp2,
    const void* __restrict__ Wp3, const void* __restrict__ bp3,
    const void* __restrict__ Wr1, const void* __restrict__ br1,
    const void* __restrict__ Wr2, const void* __restrict__ br2,
    const void* __restrict__ Wr3, const void* __restrict__ br3,
    short* __restrict__ Wp1Tp, short* __restrict__ Wp2T, short* __restrict__ Wp3T,
    short* __restrict__ Wr1T,  short* __restrict__ Wr2T,
    float* __restrict__ bp1f, float* __restrict__ bp2f, float* __restrict__ bp3f,
    float* __restrict__ br1f, float* __restrict__ br2f,
    float* __restrict__ Wr3f, float* __restrict__ br3f,
    int* __restrict__ flag)
{
    __shared__ int sflag;
    if (threadIdx.x < 64) {
        const unsigned short* w = (const unsigned short*)Wp2;
        int bad = 0;
        for (int i = threadIdx.x; i < 1024; i += 64) {
            const int e = (w[i] >> 7) & 0xFF;
            if (e >= 131) bad = 1;                // |v|>=16 / inf / nan -> f32 bits
        }
        const unsigned long long m = __ballot(bad);
        if (threadIdx.x == 0) {
            sflag = (m != 0ull) ? 1 : 0;
            if (blockIdx.x == 0) *flag = sflag;
        }
    }
    __syncthreads();
    const int f32 = sflag;

    const int stride = gridDim.x * blockDim.x;
    for (int i = blockIdx.x * blockDim.x + threadIdx.x; i < 173634; i += stride) {
        if (i < 65536) {                       // Wp2T[n][k] = Wp2[k][n]
            const int n = i >> 8, k = i & 255;
            Wp2T[i] = f2bs(ld(Wp2, (long)k * 256 + n, f32));
        } else if (i < 81920) {                // Wp3T[n][k] = Wp3[k][n]
            const int j = i - 65536, n = j >> 8, k = j & 255;
            Wp3T[j] = f2bs(ld(Wp3, (long)k * 64 + n, f32));
        } else if (i < 90112) {                // Wp1Tp[n][k<32], zero-pad k>=4
            const int j = i - 81920, n = j >> 5, k = j & 31;
            Wp1Tp[j] = (k < 4) ? f2bs(ld(Wp1, (long)k * 256 + n, f32)) : (short)0;
        } else if (i < 106496) {               // Wr1T[n][k=64]
            const int j = i - 90112, n = j >> 6, k = j & 63;
            Wr1T[j] = f2bs(ld(Wr1, (long)k * 256 + n, f32));
        } else if (i < 172032) {               // Wr2T[n][k=256]
            const int j = i - 106496, n = j >> 8, k = j & 255;
            Wr2T[j] = f2bs(ld(Wr2, (long)k * 256 + n, f32));
        } else if (i < 172288) { bp1f[i - 172032] = ld(bp1, i - 172032, f32); }
        else if (i < 172544) { bp2f[i - 172288] = ld(bp2, i - 172288, f32); }
        else if (i < 172608) { bp3f[i - 172544] = ld(bp3, i - 172544, f32); }
        else if (i < 172864) { br1f[i - 172608] = ld(br1, i - 172608, f32); }
        else if (i < 173120) { br2f[i - 172864] = ld(br2, i - 172864, f32); }
        else if (i < 173632) { Wr3f[i - 173120] = ld(Wr3, i - 173120, f32); }
        else                 { br3f[i - 173632] = ld(br3, i - 173632, f32); }
    }
}

// ---------------------------------------------------------------------------
// Edge MLP, all-MFMA with SWAPPED operands (weights = A, activations = B):
// D[n][m] -> per lane: one edge (col=ln), 4 consecutive n rows => packed b64
// epilogue writes, bias folded into MFMA C-init. 64 edges/block, 4 waves.
// ---------------------------------------------------------------------------
__global__ __launch_bounds__(256, 4) void edge_mlp_kernel(
    const void* __restrict__ ef, const int* __restrict__ ids,
    const short* __restrict__ Wp1Tp, const float* __restrict__ bp1f,
    const short* __restrict__ Wp2T, const float* __restrict__ bp2f,
    const short* __restrict__ Wp3T, const float* __restrict__ bp3f,
    float* __restrict__ agg, float* __restrict__ bar,
    const int* __restrict__ flag)
{
    __shared__ __align__(16) short hs[E * S1];     // 33.3 KB: h1, h2, then h3 overlay
    __shared__ float cb[E][2];
    __shared__ int   sid[E];

    const int t = threadIdx.x;
    const long e0 = (long)blockIdx.x * E;
    const int f32 = *flag;
    const int wave = t >> 6, lane = t & 63, quad = lane >> 4, ln = lane & 15;
    const int nb = wave * 64;

    if (t < E) {
        sid[t] = ids[e0 + t];
        const float px = ld(ef, (e0 + t) * 4 + 0, f32);
        const float py = ld(ef, (e0 + t) * 4 + 1, f32);
        const float d = sqrtf(px * px + py * py);
        const float inv = 1.0f / (d * (d - 0.18f));
        cb[t][0] = -px * inv;
        cb[t][1] = -py * inv;
    }

    // ---- layer 1: h1 = relu(x @ Wp1 + bp1); A=Wp1^T tiles, B=x frags ----
    {
        short8 b[4];                       // B-operand: edges mt*16+ln (quad 0 holds k<4)
        #pragma unroll
        for (int mt = 0; mt < 4; ++mt) {
            short8 v = {};
            if (quad == 0) {
                const long e = e0 + mt * 16 + ln;
                if (f32) {
                    const float4 x = ((const float4*)ef)[e];
                    v[0] = f2bs(x.x); v[1] = f2bs(x.y); v[2] = f2bs(x.z); v[3] = f2bs(x.w);
                } else {
                    const int2 x = ((const int2*)ef)[e];
                    v[0] = (short)(x.x & 0xffff); v[1] = (short)((unsigned)x.x >> 16);
                    v[2] = (short)(x.y & 0xffff); v[3] = (short)((unsigned)x.y >> 16);
                }
            }
            b[mt] = v;
        }
        floatx4 acc[4][4];                 // [mt][nt], init = bias rows
        #pragma unroll
        for (int nt = 0; nt < 4; ++nt) {
            const float4 bv = *(const float4*)&bp1f[nb + nt * 16 + quad * 4];
            const floatx4 bi = { bv.x, bv.y, bv.z, bv.w };
            #pragma unroll
            for (int mt = 0; mt < 4; ++mt) acc[mt][nt] = bi;
        }
        #pragma unroll
        for (int nt = 0; nt < 4; ++nt) {
            const short8 a = *(const short8*)&Wp1Tp[(nb + nt * 16 + ln) * 32 + quad * 8];
            #pragma unroll
            for (int mt = 0; mt < 4; ++mt)
                acc[mt][nt] = __builtin_amdgcn_mfma_f32_16x16x32_bf16(a, b[mt], acc[mt][nt], 0, 0, 0);
        }
        #pragma unroll
        for (int mt = 0; mt < 4; ++mt)
            #pragma unroll
            for (int nt = 0; nt < 4; ++nt) {
                const floatx4 v = acc[mt][nt];
                uint2 w;
                w.x = pk(fmaxf(v[0], 0.f), fmaxf(v[1], 0.f));
                w.y = pk(fmaxf(v[2], 0.f), fmaxf(v[3], 0.f));
                *(uint2*)&hs[(mt * 16 + ln) * S1 + nb + nt * 16 + quad * 4] = w;
            }
    }
    __syncthreads();

    // ---- layer 2: h2 = relu(h1 @ Wp2 + bp2); A=Wp2^T (prefetched), B=h1 ----
    {
        floatx4 acc[4][4];
        #pragma unroll
        for (int nt = 0; nt < 4; ++nt) {
            const float4 bv = *(const float4*)&bp2f[nb + nt * 16 + quad * 4];
            const floatx4 bi = { bv.x, bv.y, bv.z, bv.w };
            #pragma unroll
            for (int mt = 0; mt < 4; ++mt) acc[mt][nt] = bi;
        }
        short8 wcur[4], wnxt[4];
        #pragma unroll
        for (int nt = 0; nt < 4; ++nt)
            wcur[nt] = *(const short8*)&Wp2T[(nb + nt * 16 + ln) * 256 + quad * 8];
        #pragma unroll
        for (int ks = 0; ks < 8; ++ks) {
            if (ks < 7) {
                #pragma unroll
                for (int nt = 0; nt < 4; ++nt)
                    wnxt[nt] = *(const short8*)&Wp2T[(nb + nt * 16 + ln) * 256 + (ks + 1) * 32 + quad * 8];
            }
            short8 b[4];
            #pragma unroll
            for (int mt = 0; mt < 4; ++mt)
                b[mt] = *(const short8*)&hs[(mt * 16 + ln) * S1 + ks * 32 + quad * 8];
            #pragma unroll
            for (int mt = 0; mt < 4; ++mt)
                #pragma unroll
                for (int nt = 0; nt < 4; ++nt)
                    acc[mt][nt] = __builtin_amdgcn_mfma_f32_16x16x32_bf16(wcur[nt], b[mt], acc[mt][nt], 0, 0, 0);
            #pragma unroll
            for (int nt = 0; nt < 4; ++nt) wcur[nt] = wnxt[nt];
        }
        __syncthreads();   // all h1 reads complete before overwrite
        #pragma unroll
        for (int mt = 0; mt < 4; ++mt)
            #pragma unroll
            for (int nt = 0; nt < 4; ++nt) {
                const floatx4 v = acc[mt][nt];
                uint2 w;
                w.x = pk(fmaxf(v[0], 0.f), fmaxf(v[1], 0.f));
                w.y = pk(fmaxf(v[2], 0.f), fmaxf(v[3], 0.f));
                *(uint2*)&hs[(mt * 16 + ln) * S1 + nb + nt * 16 + quad * 4] = w;
            }
    }
    __syncthreads();

    // ---- layer 3: h3 = h2 @ Wp3 + bp3; per-wave 16-edge tile, float4 out ----
    // h3 overlays the wave's OWN 16-row quarter of hs; all reads precede
    // writes in wave program order (DS in-order) => no barrier needed after.
    float* h3f = (float*)&hs[wave * 16 * S1];
    {
        floatx4 acc[4];
        #pragma unroll
        for (int nt = 0; nt < 4; ++nt) {
            const float4 bv = *(const float4*)&bp3f[nt * 16 + quad * 4];
            acc[nt] = (floatx4){ bv.x, bv.y, bv.z, bv.w };
        }
        #pragma unroll 2
        for (int ks = 0; ks < 8; ++ks) {
            const short8 b = *(const short8*)&hs[(wave * 16 + ln) * S1 + ks * 32 + quad * 8];
            #pragma unroll
            for (int nt = 0; nt < 4; ++nt) {
                const short8 a = *(const short8*)&Wp3T[(nt * 16 + ln) * 256 + ks * 32 + quad * 8];
                acc[nt] = __builtin_amdgcn_mfma_f32_16x16x32_bf16(a, b, acc[nt], 0, 0, 0);
            }
        }
        #pragma unroll
        for (int nt = 0; nt < 4; ++nt) {
            float4 v = { acc[nt][0], acc[nt][1], acc[nt][2], acc[nt][3] };
            *(float4*)&h3f[ln * SH3 + nt * 16 + quad * 4] = v;   // row=local edge ln
        }
    }

    // ---- scatter: each wave handles its own 16-edge window (ids sorted) ----
    {
        const int w0 = wave * 16;
        const int f = lane;                     // feature 0..63
        int cur = sid[w0];
        float local = h3f[f];
        #pragma unroll
        for (int e = 1; e < 16; ++e) {
            const int id = sid[w0 + e];
            const float v = h3f[e * SH3 + f];
            if (id == cur) local += v;
            else { atomicAdd(&agg[(long)cur * 64 + f], local); cur = id; local = v; }
        }
        atomicAdd(&agg[(long)cur * 64 + f], local);

        if (lane < 2) {
            int c2 = sid[w0];
            float l2 = cb[w0][lane];
            #pragma unroll
            for (int e = 1; e < 16; ++e) {
                const int id = sid[w0 + e];
                const float v = cb[w0 + e][lane];
                if (id == c2) l2 += v;
                else { atomicAdd(&bar[c2 * 2 + lane], l2); c2 = id; l2 = v; }
            }
            atomicAdd(&bar[c2 * 2 + lane], l2);
        }
    }
}

// ---------------------------------------------------------------------------
// Agent MLP, all-MFMA, swapped operands. 32 agents/block, 512 blocks.
// ---------------------------------------------------------------------------
__global__ __launch_bounds__(256, 2) void agent_mlp_kernel(
    const float* __restrict__ agg, const float* __restrict__ bar,
    const short* __restrict__ Wr1T, const float* __restrict__ br1f,
    const short* __restrict__ Wr2T, const float* __restrict__ br2f,
    const float* __restrict__ Wr3f, const float* __restrict__ br3f,
    void* __restrict__ out, const int* __restrict__ flag)
{
    __shared__ __align__(16) short ha[AG * 68];    // bf16 agg (4.4 KB)
    __shared__ __align__(16) short hs[AG * S1];    // r1, then r2 (16.6 KB)
    __shared__ float part[8][AG][2];

    const int t = threadIdx.x;
    const int a0 = blockIdx.x * AG;
    const int f32 = *flag;
    const int wave = t >> 6, lane = t & 63, quad = lane >> 4, ln = lane & 15;
    const int nb = wave * 64;

    #pragma unroll
    for (int i = 0; i < 2; ++i) {
        const float4 x = ((const float4*)agg)[(long)blockIdx.x * 512 + i * 256 + t];
        const int idx4 = (i * 256 + t) * 4;
        s16x4 v = { f2bs(x.x), f2bs(x.y), f2bs(x.z), f2bs(x.w) };
        *(s16x4*)&ha[(idx4 >> 6) * 68 + (idx4 & 63)] = v;
    }
    __syncthreads();

    // ---- r1 = relu(a @ Wr1 + br1), K=64, M=32 ----
    {
        floatx4 acc[2][4];
        #pragma unroll
        for (int nt = 0; nt < 4; ++nt) {
            const float4 bv = *(const float4*)&br1f[nb + nt * 16 + quad * 4];
            const floatx4 bi = { bv.x, bv.y, bv.z, bv.w };
            #pragma unroll
            for (int mt = 0; mt < 2; ++mt) acc[mt][nt] = bi;
        }
        #pragma unroll
        for (int ks = 0; ks < 2; ++ks) {
            short8 b[2], a[4];
            #pragma unroll
            for (int mt = 0; mt < 2; ++mt)
                b[mt] = *(const short8*)&ha[(mt * 16 + ln) * 68 + ks * 32 + quad * 8];
            #pragma unroll
            for (int nt = 0; nt < 4; ++nt)
                a[nt] = *(const short8*)&Wr1T[(nb + nt * 16 + ln) * 64 + ks * 32 + quad * 8];
            #pragma unroll
            for (int mt = 0; mt < 2; ++mt)
                #pragma unroll
                for (int nt = 0; nt < 4; ++nt)
                    acc[mt][nt] = __builtin_amdgcn_mfma_f32_16x16x32_bf16(a[nt], b[mt], acc[mt][nt], 0, 0, 0);
        }
        #pragma unroll
        for (int mt = 0; mt < 2; ++mt)
            #pragma unroll
            for (int nt = 0; nt < 4; ++nt) {
                const floatx4 v = acc[mt][nt];
                uint2 w;
                w.x = pk(fmaxf(v[0], 0.f), fmaxf(v[1], 0.f));
                w.y = pk(fmaxf(v[2], 0.f), fmaxf(v[3], 0.f));
                *(uint2*)&hs[(mt * 16 + ln) * S1 + nb + nt * 16 + quad * 4] = w;
            }
    }
    __syncthreads();

    // ---- r2 = relu(r1 @ Wr2 + br2), K=256, single-buffer ----
    {
        floatx4 acc[2][4];
        #pragma unroll
        for (int nt = 0; nt < 4; ++nt) {
            const float4 bv = *(const float4*)&br2f[nb + nt * 16 + quad * 4];
            const floatx4 bi = { bv.x, bv.y, bv.z, bv.w };
            #pragma unroll
            for (int mt = 0; mt < 2; ++mt) acc[mt][nt] = bi;
        }
        short8 wcur[4], wnxt[4];
        #pragma unroll
        for (int nt = 0; nt < 4; ++nt)
            wcur[nt] = *(const short8*)&Wr2T[(nb + nt * 16 + ln) * 256 + quad * 8];
        #pragma unroll
        for (int ks = 0; ks < 8; ++ks) {
            if (ks < 7) {
                #pragma unroll
                for (int nt = 0; nt < 4; ++nt)
                    wnxt[nt] = *(const short8*)&Wr2T[(nb + nt * 16 + ln) * 256 + (ks + 1) * 32 + quad * 8];
            }
            short8 b[2];
            #pragma unroll
            for (int mt = 0; mt < 2; ++mt)
                b[mt] = *(const short8*)&hs[(mt * 16 + ln) * S1 + ks * 32 + quad * 8];
            #pragma unroll
            for (int mt = 0; mt < 2; ++mt)
                #pragma unroll
                for (int nt = 0; nt < 4; ++nt)
                    acc[mt][nt] = __builtin_amdgcn_mfma_f32_16x16x32_bf16(wcur[nt], b[mt], acc[mt][nt], 0, 0, 0);
            #pragma unroll
            for (int nt = 0; nt < 4; ++nt) wcur[nt] = wnxt[nt];
        }
        __syncthreads();
        #pragma unroll
        for (int mt = 0; mt < 2; ++mt)
            #pragma unroll
            for (int nt = 0; nt < 4; ++nt) {
                const floatx4 v = acc[mt][nt];
                uint2 w;
                w.x = pk(fmaxf(v[0], 0.f), fmaxf(v[1], 0.f));
                w.y = pk(fmaxf(v[2], 0.f), fmaxf(v[3], 0.f));
                *(uint2*)&hs[(mt * 16 + ln) * S1 + nb + nt * 16 + quad * 4] = w;
            }
    }
    __syncthreads();

    // ---- out = r2 @ Wr3 + br3 + bar (N=2, VALU, 8-way K-split) ----
    {
        const int m = t & 31;
        const int p = t >> 5;                     // 8 K-partitions of 32
        float v0 = 0.f, v1 = 0.f;
        #pragma unroll
        for (int kk = 0; kk < 4; ++kk) {
            const int k0 = p * 32 + kk * 8;
            const short8 h = *(const short8*)&hs[m * S1 + k0];
            #pragma unroll
            for (int j = 0; j < 8; ++j) {
                const float hv = bs2f(h[j]);
                v0 = fmaf(hv, Wr3f[(k0 + j) * 2 + 0], v0);
                v1 = fmaf(hv, Wr3f[(k0 + j) * 2 + 1], v1);
            }
        }
        part[p][m][0] = v0;
        part[p][m][1] = v1;
    }
    __syncthreads();
    if (t < 64) {
        const int m = t >> 1, o = t & 1;
        float s = br3f[o] + bar[(long)(a0 + m) * 2 + o];
        #pragma unroll
        for (int p = 0; p < 8; ++p) s += part[p][m][o];
        if (f32) ((float*)out)[(a0 + m) * 2 + o] = s;
        else     ((bf16*)out)[(a0 + m) * 2 + o] = __float2bfloat16(s);
    }
}

extern "C" void kernel_launch(void* const* d_in, const int* in_sizes, int n_in,
                              void* d_out, int out_size, void* d_ws, size_t ws_size,
                              hipStream_t stream)
{
    (void)in_sizes; (void)n_in; (void)out_size;

    const void* ef  = d_in[0];
    const int*  ids = (const int*)d_in[1];

    char* p = (char*)d_ws;
    int*   flag  = (int*)p;        p += 256;
    float* agg   = (float*)p;      p += (size_t)NA * 64 * 4;
    float* bar   = (float*)p;      p += (size_t)NA * 2 * 4;
    short* Wp1Tp = (short*)p;      p += 8192 * 2;
    short* Wp2T  = (short*)p;      p += 65536 * 2;
    short* Wp3T  = (short*)p;      p += 16384 * 2;
    short* Wr1T  = (short*)p;      p += 16384 * 2;
    short* Wr2T  = (short*)p;      p += 65536 * 2;
    float* bp1f  = (float*)p;      p += 256 * 4;
    float* bp2f  = (float*)p;      p += 256 * 4;
    float* bp3f  = (float*)p;      p += 64 * 4;
    float* br1f  = (float*)p;      p += 256 * 4;
    float* br2f  = (float*)p;      p += 256 * 4;
    float* Wr3f  = (float*)p;      p += 512 * 4;
    float* br3f  = (float*)p;      p += 256;
    const size_t required = (size_t)(p - (char*)d_ws);
    if (ws_size < required) return;  // signature: output stays zero (absmax ~26)

    hipMemsetAsync(agg, 0, ((size_t)NA * 64 + (size_t)NA * 2) * 4, stream);
    prep_weights_kernel<<<64, 256, 0, stream>>>(
        d_in[2], d_in[3], d_in[4], d_in[5], d_in[6], d_in[7],
        d_in[8], d_in[9], d_in[10], d_in[11], d_in[12], d_in[13],
        Wp1Tp, Wp2T, Wp3T, Wr1T, Wr2T,
        bp1f, bp2f, bp3f, br1f, br2f, Wr3f, br3f, flag);
    edge_mlp_kernel<<<NE / E, 256, 0, stream>>>(
        ef, ids, Wp1Tp, bp1f, Wp2T, bp2f, Wp3T, bp3f, agg, bar, flag);
    agent_mlp_kernel<<<NA / AG, 256, 0, stream>>>(
        agg, bar, Wr1T, br1f, Wr2T, br2f, Wr3f, br3f, d_out, flag);
}